// Round 5
// baseline (4501.889 us; speedup 1.0000x reference)
//
#include <hip/hip_runtime.h>
#include <cstddef>

// Problem constants
#define Bb 128
#define Tt 512
#define Ii 256
#define Hh 512
#define G4c 2048      // 4*H
#define BHc (Bb * Hh) // elements in one h buffer

typedef float    f32x4 __attribute__((ext_vector_type(4)));
typedef _Float16 f16x8 __attribute__((ext_vector_type(8)));
typedef unsigned int u32x4 __attribute__((ext_vector_type(4)));

// ws layout (bytes)
#define OFF_WT1 0u
#define OFF_WT2 3145728u          // 32jb*24ks*4g*64ln*8i*2B
#define OFF_BC1 7340032u          // +32jb*32ks*4g*64ln*8i*2B
#define OFF_BC2 7348224u
#define OFF_H1  7356416u          // 2*128*512*2
#define OFF_H2  7618560u
#define OFF_H2F 7880704u          // 128*512*4
#define OFF_FLG 8142848u          // 128 u32 flags (2 groups of 64)
#define OFF_END 8143360u

__device__ __forceinline__ float sigm(float x)  { return 1.0f / (1.0f + __expf(-x)); }
__device__ __forceinline__ float tanhf_(float x){ return 1.0f - 2.0f / (1.0f + __expf(2.0f * x)); }

// ---- coherent (cross-XCD) memory ops: bypass non-coherent L2 via sc0 sc1 ----
__device__ __forceinline__ void ld_g_f16x8_sc(f16x8& dst, const _Float16* p) {
  asm volatile("global_load_dwordx4 %0, %1, off sc0 sc1"
               : "=v"(dst) : "v"(p) : "memory");
}
__device__ __forceinline__ void ld_g_f32x4(f32x4& dst, const float* p) {
  asm volatile("global_load_dwordx4 %0, %1, off"
               : "=v"(dst) : "v"(p) : "memory");
}
__device__ __forceinline__ void st_g_f16_sc(_Float16* p, _Float16 v) {
  unsigned u = (unsigned)__builtin_bit_cast(unsigned short, v);
  asm volatile("global_store_short %0, %1, off sc0 sc1" :: "v"(p), "v"(u) : "memory");
}
__device__ __forceinline__ void st_g_f32_sc(float* p, float v) {
  asm volatile("global_store_dword %0, %1, off sc0 sc1" :: "v"(p), "v"(v) : "memory");
}
__device__ __forceinline__ void wait_vm0() {
  asm volatile("s_waitcnt vmcnt(0)" ::: "memory");
}

// Flag barrier over the 64 blocks of one rh-group (round-2 proven).
__device__ __forceinline__ void flag_barrier(unsigned* grp, unsigned* myflag,
                                             int tid, unsigned target) {
  wait_vm0();            // per-wave: drain this wave's sc1 data stores
  __syncthreads();       // all waves drained
  if (tid < 64) {
    if (tid == 0) {
      __hip_atomic_store(myflag, target, __ATOMIC_RELAXED, __HIP_MEMORY_SCOPE_AGENT);
      wait_vm0();        // own flag at coherent point before polling
    }
    unsigned v;
    do {
      v = __hip_atomic_load(grp + tid, __ATOMIC_RELAXED, __HIP_MEMORY_SCOPE_AGENT);
    } while (__any(v < target));
  }
  __syncthreads();
}

// Pack weights FRAGMENT-MAJOR: WtF[jb][ks][g][lane][i] =
//   W_cat[k = ks*32 + (lane>>4)*8 + i][gcol = g*512 + jb*16 + (lane&15)]
// so the kernel's B-read is smem + (ks*4+g)*1024 + lane*16 (conflict-free b128).
// Grid: 4096 blocks = (layer<<11)|(jb<<6)|ln, 256 threads = (ks<<3)|i.
__global__ void init_weights(const float* __restrict__ Wx1, const float* __restrict__ Wh1,
                             const float* __restrict__ bx1, const float* __restrict__ bh1,
                             const float* __restrict__ Wx2, const float* __restrict__ Wh2,
                             const float* __restrict__ bx2, const float* __restrict__ bh2,
                             _Float16* __restrict__ Wt1, _Float16* __restrict__ Wt2,
                             float* __restrict__ bc1, float* __restrict__ bc2) {
  const int b = blockIdx.x;
  const int layer = b >> 11;
  const int jb = (b >> 6) & 31;
  const int ln = b & 63;
  const int t  = threadIdx.x;
  const int ks = t >> 3;
  const int i  = t & 7;
  const int k  = (ks << 5) + ((ln >> 4) << 3) + i;
  if (layer == 0) {
    if (ln == 0 && t < 16) {
      #pragma unroll
      for (int g = 0; g < 4; ++g) {
        const int gc = (g << 9) + (jb << 4) + t;
        bc1[gc] = bx1[gc] + bh1[gc];
      }
    }
    if (ks < 24) {
      #pragma unroll
      for (int g = 0; g < 4; ++g) {
        const int gc = (g << 9) + (jb << 4) + (ln & 15);
        const float v = (k < Ii) ? Wx1[k * G4c + gc] : Wh1[(k - Ii) * G4c + gc];
        Wt1[((((size_t)jb * 24 + ks) * 4 + g) * 64 + ln) * 8 + i] = (_Float16)v;
      }
    }
  } else {
    if (ln == 0 && t < 16) {
      #pragma unroll
      for (int g = 0; g < 4; ++g) {
        const int gc = (g << 9) + (jb << 4) + t;
        bc2[gc] = bx2[gc] + bh2[gc];
      }
    }
    #pragma unroll
    for (int g = 0; g < 4; ++g) {
      const int gc = (g << 9) + (jb << 4) + (ln & 15);
      const float v = (k < Hh) ? Wx2[k * G4c + gc] : Wh2[(k - Hh) * G4c + gc];
      Wt2[((((size_t)jb * 32 + ks) * 4 + g) * 64 + ln) * 8 + i] = (_Float16)v;
    }
  }
}

__global__ void zero_ws(u32x4* p, int n) {
  const int i = blockIdx.x * blockDim.x + threadIdx.x;
  if (i < n) p[i] = (u32x4){0u, 0u, 0u, 0u};
}

// Persistent cooperative kernel (round-2 structure; fragment-major LDS B).
// 128 blocks: bid>>6 = layer; blkL = bid&63; jb = blkL>>1 (16 H-cols at j0);
// rh = blkL&1 (rows rh*64..+63). Wave wv owns 16-row band.
// Epoch e: layer1 computes t=e (e<512); layer2 computes t=e-1 (e>=1).
__global__ __launch_bounds__(256, 1) void lstm_main(
    const float* __restrict__ x,
    const _Float16* __restrict__ Wt1, const _Float16* __restrict__ Wt2,
    const float* __restrict__ bc1, const float* __restrict__ bc2,
    _Float16* h1buf, _Float16* h2buf, float* h2f, unsigned* flags,
    const float* __restrict__ Whead, const float* __restrict__ bhead,
    float* __restrict__ out)
{
  extern __shared__ char smem[];

  const int tid  = threadIdx.x;
  const int lane = tid & 63;
  const int wv   = tid >> 6;          // wave 0..3 -> 16-row band
  const int bid  = blockIdx.x;
  const int layer = bid >> 6;
  const int blkL  = bid & 63;
  const int jb = blkL >> 1;
  const int rh = blkL & 1;
  const int j0 = jb << 4;

  unsigned* grp = flags + (rh << 6);
  unsigned* myflag = grp + (layer << 5) + jb;

  // ---- stage fragment-major weight slice into LDS (flat copy) ----
  {
    const int elems16 = layer ? (131072 / 16) : (98304 / 16);
    const u32x4* src = (const u32x4*)((layer ? Wt2 : Wt1)
                                      + (size_t)jb * (layer ? 65536 : 49152));
    u32x4* dst = (u32x4*)smem;
    for (int i = tid; i < elems16; i += 256) dst[i] = src[i];
  }
  __syncthreads();

  const int c15 = lane & 15;           // MFMA row (A) / col (B,D)
  const int kg  = lane >> 4;           // k-group
  const int arow  = (rh << 6) + (wv << 4) + c15;          // batch row for A frags
  const int wrow0 = (rh << 6) + (wv << 4) + (kg << 2);    // first D row

  const float* bc = layer ? bc2 : bc1;
  const float bias0 = bc[        j0 + c15];
  const float bias1 = bc[ 512 +  j0 + c15];
  const float bias2 = bc[1024 +  j0 + c15];
  const float bias3 = bc[1536 +  j0 + c15];

  const int lb = lane << 4;            // lane byte offset into each 1KB fragment row

  f32x4 cst = {0.f, 0.f, 0.f, 0.f};  // c-state, f32, registers

  for (int e = 0; e <= Tt; ++e) {
    const bool active = layer ? (e >= 1) : (e < Tt);
    if (active) {
      f32x4 acc0 = {0.f,0.f,0.f,0.f}, acc1 = {0.f,0.f,0.f,0.f};
      f32x4 acc2 = {0.f,0.f,0.f,0.f}, acc3 = {0.f,0.f,0.f,0.f};
      if (layer == 0) {
        // A: x_t (k 0..255, f32->f16, plain cached) then h1(e-1) (sc), one burst
        f32x4 xf[16];
        f16x8 af[24];
        const float* xp = x + (size_t)arow * (Tt * Ii) + (size_t)e * Ii + (kg << 3);
        #pragma unroll
        for (int ks = 0; ks < 8; ++ks) {
          ld_g_f32x4(xf[2*ks],   xp + (ks << 5));
          ld_g_f32x4(xf[2*ks+1], xp + (ks << 5) + 4);
        }
        const _Float16* hp = h1buf + ((e + 1) & 1) * BHc + arow * Hh + (kg << 3);
        #pragma unroll
        for (int ks = 0; ks < 16; ++ks)
          ld_g_f16x8_sc(af[8 + ks], hp + (ks << 5));
        wait_vm0();
        __builtin_amdgcn_sched_barrier(0);
        #pragma unroll
        for (int ks = 0; ks < 8; ++ks) {
          f16x8 v;
          v[0] = (_Float16)xf[2*ks][0]; v[1] = (_Float16)xf[2*ks][1];
          v[2] = (_Float16)xf[2*ks][2]; v[3] = (_Float16)xf[2*ks][3];
          v[4] = (_Float16)xf[2*ks+1][0]; v[5] = (_Float16)xf[2*ks+1][1];
          v[6] = (_Float16)xf[2*ks+1][2]; v[7] = (_Float16)xf[2*ks+1][3];
          af[ks] = v;
        }
        #pragma unroll
        for (int ks = 0; ks < 24; ++ks) {
          const char* bp = smem + (ks << 12) + lb;   // (ks*4+g)*1024 + lane*16
          acc0 = __builtin_amdgcn_mfma_f32_16x16x32_f16(af[ks], *(const f16x8*)(bp         ), acc0, 0, 0, 0);
          acc1 = __builtin_amdgcn_mfma_f32_16x16x32_f16(af[ks], *(const f16x8*)(bp + 1024  ), acc1, 0, 0, 0);
          acc2 = __builtin_amdgcn_mfma_f32_16x16x32_f16(af[ks], *(const f16x8*)(bp + 2048  ), acc2, 0, 0, 0);
          acc3 = __builtin_amdgcn_mfma_f32_16x16x32_f16(af[ks], *(const f16x8*)(bp + 3072  ), acc3, 0, 0, 0);
        }
      } else {
        f16x8 af[32];
        const _Float16* h1p = h1buf + ((e + 1) & 1) * BHc + arow * Hh + (kg << 3);
        const _Float16* h2p = h2buf + (e & 1) * BHc + arow * Hh + (kg << 3);
        #pragma unroll
        for (int ks = 0; ks < 16; ++ks)
          ld_g_f16x8_sc(af[ks], h1p + (ks << 5));
        #pragma unroll
        for (int ks = 0; ks < 16; ++ks)
          ld_g_f16x8_sc(af[16 + ks], h2p + (ks << 5));
        wait_vm0();
        __builtin_amdgcn_sched_barrier(0);
        #pragma unroll
        for (int ks = 0; ks < 32; ++ks) {
          const char* bp = smem + (ks << 12) + lb;
          acc0 = __builtin_amdgcn_mfma_f32_16x16x32_f16(af[ks], *(const f16x8*)(bp         ), acc0, 0, 0, 0);
          acc1 = __builtin_amdgcn_mfma_f32_16x16x32_f16(af[ks], *(const f16x8*)(bp + 1024  ), acc1, 0, 0, 0);
          acc2 = __builtin_amdgcn_mfma_f32_16x16x32_f16(af[ks], *(const f16x8*)(bp + 2048  ), acc2, 0, 0, 0);
          acc3 = __builtin_amdgcn_mfma_f32_16x16x32_f16(af[ks], *(const f16x8*)(bp + 3072  ), acc3, 0, 0, 0);
        }
      }
      // gates -> c,h (D layout: row = kg*4 + r, col = c15)
      float hout[4];
      #pragma unroll
      for (int r = 0; r < 4; ++r) {
        const float iv = sigm(acc0[r] + bias0);
        const float fv = sigm(acc1[r] + bias1);
        const float gv = tanhf_(acc2[r] + bias2);
        const float ov = sigm(acc3[r] + bias3);
        const float cv = fv * cst[r] + iv * gv;
        cst[r] = cv;
        hout[r] = ov * tanhf_(cv);
      }
      _Float16* hw = layer ? (h2buf + ((e + 1) & 1) * BHc) : (h1buf + (e & 1) * BHc);
      #pragma unroll
      for (int r = 0; r < 4; ++r)
        st_g_f16_sc(hw + (size_t)(wrow0 + r) * Hh + j0 + c15, (_Float16)hout[r]);
      if (layer == 1 && e == Tt) {
        #pragma unroll
        for (int r = 0; r < 4; ++r)
          st_g_f32_sc(h2f + (size_t)(wrow0 + r) * Hh + j0 + c15, hout[r]);
      }
    }
    flag_barrier(grp, myflag, tid, (unsigned)(e + 1));
  }

  // head: out[b][c] = h2_T[b,:] . W_head[:,c] + b_head[c]  (round-2 proven)
  if (layer == 1 && jb == 0) {
    const int b_ = (rh << 6) + (tid >> 2);
    const int cc = tid & 3;
    const float* hr = h2f + (size_t)b_ * Hh;
    float s = bhead[cc];
    #pragma unroll 4
    for (int k = 0; k < Hh; k += 4) {
      const f32x4 hv = *(const f32x4*)(hr + k);
      s += hv[0] * Whead[(k + 0) * 4 + cc];
      s += hv[1] * Whead[(k + 1) * 4 + cc];
      s += hv[2] * Whead[(k + 2) * 4 + cc];
      s += hv[3] * Whead[(k + 3) * 4 + cc];
    }
    out[b_ * 4 + cc] = s;
  }
}

extern "C" void kernel_launch(void* const* d_in, const int* in_sizes, int n_in,
                              void* d_out, int out_size, void* d_ws, size_t ws_size,
                              hipStream_t stream) {
  const float* x   = (const float*)d_in[0];
  const float* Wx1 = (const float*)d_in[1];
  const float* bx1 = (const float*)d_in[2];
  const float* Wh1 = (const float*)d_in[3];
  const float* bh1 = (const float*)d_in[4];
  const float* Wx2 = (const float*)d_in[5];
  const float* bx2 = (const float*)d_in[6];
  const float* Wh2 = (const float*)d_in[7];
  const float* bh2 = (const float*)d_in[8];
  const float* Whd = (const float*)d_in[9];
  const float* bhd = (const float*)d_in[10];

  char* ws = (char*)d_ws;
  _Float16* Wt1 = (_Float16*)(ws + OFF_WT1);
  _Float16* Wt2 = (_Float16*)(ws + OFF_WT2);
  float* bc1 = (float*)(ws + OFF_BC1);
  float* bc2 = (float*)(ws + OFF_BC2);
  _Float16* h1b = (_Float16*)(ws + OFF_H1);
  _Float16* h2b = (_Float16*)(ws + OFF_H2);
  float* h2f = (float*)(ws + OFF_H2F);
  unsigned* flg = (unsigned*)(ws + OFF_FLG);
  float* out = (float*)d_out;

  init_weights<<<4096, 256, 0, stream>>>(Wx1, Wh1, bx1, bh1, Wx2, Wh2, bx2, bh2,
                                         Wt1, Wt2, bc1, bc2);
  {
    u32x4* zp = (u32x4*)(ws + OFF_H1);
    const int n = (int)((OFF_END - OFF_H1) / 16);  // zero h buffers + h2f + flags
    zero_ws<<<(n + 255) / 256, 256, 0, stream>>>(zp, n);
  }
  (void)hipFuncSetAttribute((const void*)lstm_main,
                            hipFuncAttributeMaxDynamicSharedMemorySize, 131072);
  void* args[] = {(void*)&x, (void*)&Wt1, (void*)&Wt2, (void*)&bc1, (void*)&bc2,
                  (void*)&h1b, (void*)&h2b, (void*)&h2f, (void*)&flg,
                  (void*)&Whd, (void*)&bhd, (void*)&out};
  (void)hipLaunchCooperativeKernel((const void*)lstm_main, dim3(128), dim3(256),
                                   args, 131072, stream);
}